// Round 5
// baseline (282.293 us; speedup 1.0000x reference)
//
#include <hip/hip_runtime.h>

#define NATOMS 20000
#define NCHAN  64
#define K2 120

// ws layout (bytes) -- total 559104 B, well under any plausible ws_size:
//   [0 .. 524288)        W2bf bf16[64][4096]  c*4096 + x*256 + (y*16+i)
//   [524288 .. 557056)   W1bf bf16[64][256]   c*256 + x*16 + y
//   [557056 .. 559104)   W0bf bf16[64][16]    c*16 + x
#define W1_OFF_B 524288
#define W0_OFF_B 557056

typedef __attribute__((ext_vector_type(8))) short bf16x8;
typedef __attribute__((ext_vector_type(4))) float f32x4;

__device__ inline short f2bf_rne(float x) {
    union { float f; unsigned u; } v; v.f = x;
    unsigned r = v.u + 0x7FFF + ((v.u >> 16) & 1);
    return (short)(r >> 16);
}
// pack two f32 -> packed bf16 (round-half-up): low16 = a, high16 = b
__device__ inline unsigned pk_bf(float a, float b) {
    unsigned au = __float_as_uint(a) + 0x8000u;
    unsigned bu = __float_as_uint(b) + 0x8000u;
    return __builtin_amdgcn_perm(bu, au, 0x07060302u);
}

// ---------------------------------------------------------------------------
// Kernel 1: fold weights -> bf16 per-channel tensors (identical to round 4,
// numerics verified). 1092 blocks; W2 rows wave-uniform, w2 reads coalesced.
// ---------------------------------------------------------------------------
__global__ __launch_bounds__(256) void precompute_kernel(
    const float* __restrict__ U2, const float* __restrict__ U1,
    const float* __restrict__ U0, const float* __restrict__ w2,
    const float* __restrict__ w1, const float* __restrict__ w0,
    void* __restrict__ wsv)
{
    short* W2bf = (short*)wsv;
    short* W1bf = (short*)((char*)wsv + W1_OFF_B);
    short* W0bf = (short*)((char*)wsv + W0_OFF_B);
    const int b = blockIdx.x, t = threadIdx.x;

    if (b < 1024) {
        const int row = b * 4 + (t >> 6);         // 0..4095, uniform per wave
        const int c   = t & 63;
        const float* u = U2 + (size_t)row * K2;
        float a0 = 0.f, a1 = 0.f, a2 = 0.f, a3 = 0.f;
        #pragma unroll 6
        for (int k = 0; k < K2; k += 4) {
            a0 += u[k]     * w2[(k)     * NCHAN + c];
            a1 += u[k + 1] * w2[(k + 1) * NCHAN + c];
            a2 += u[k + 2] * w2[(k + 2) * NCHAN + c];
            a3 += u[k + 3] * w2[(k + 3) * NCHAN + c];
        }
        W2bf[c * 4096 + row] = f2bf_rne((a0 + a1) + (a2 + a3));
    } else if (b < 1088) {
        const int id = (b - 1024) * 256 + t;
        const int c = id >> 8, xy = id & 255;
        const float* u = U1 + xy * 8;
        float a = 0.f;
        #pragma unroll
        for (int k = 0; k < 8; ++k) a += u[k] * w1[k * NCHAN + c];
        W1bf[c * 256 + xy] = f2bf_rne(a);
    } else {
        const int id = (b - 1088) * 256 + t;
        const int c = id >> 4, x = id & 15;
        const float* u = U0 + x * 4;
        float a = 0.f;
        #pragma unroll
        for (int k = 0; k < 4; ++k) a += u[k] * w0[k * NCHAN + c];
        W0bf[c * 16 + x] = f2bf_rne(a);
    }
}

// ---------------------------------------------------------------------------
// Kernel 2: block = 32 atoms x 32 channels, 4 waves (each wave: 8 channels x
// 2 atom-tiles). Transposed MFMA: D[x][atom] = W2ext^T . P^T, so each lane's
// epilogue dot uses its OWN atom's f registers -- no cross-lane f staging.
//   A-frag (lane q,m elem j) = W2ext[k=ch*32+q*8+j][x=m]   (same bytes as the
//   old B-frag), B-frag = P[atom=m][k] = f_y*f_i (same bytes as old A-frag).
// Results accumulate in a 4 KB LDS tile; one fully-coalesced row writeout
// per block (each block owns complete 128B half-rows of out) -> no write amp.
// 625*32 == 20000 exactly -> no bounds checks anywhere.
// ---------------------------------------------------------------------------
__global__ __launch_bounds__(256) void contract_kernel(
    const float* __restrict__ nf,   // [N, 64, 16]
    const void* __restrict__ wsv,
    float* __restrict__ out)        // [N, 64]
{
    const short* W2g = (const short*)wsv;
    const short* W1g = (const short*)((const char*)wsv + W1_OFF_B);
    const short* W0g = (const short*)((const char*)wsv + W0_OFF_B);

    __shared__ float Ot[32][33];      // [c_local][atom_local], padded

    const int tid  = threadIdx.x;
    const int wave = tid >> 6, lane = tid & 63;
    const int m = lane & 15, q = lane >> 4;
    const int c0    = blockIdx.y * 32 + wave * 8;   // this wave's 8 channels
    const int nBase = blockIdx.x * 32;              // this block's 32 atoms

    #pragma unroll 1
    for (int ch = 0; ch < 8; ++ch) {
        const int c = c0 + ch;

        // --- A-side fragments (W2ext), loaded once per channel, reused 2x ---
        const short* Wc = W2g + (size_t)c * 4096;
        bf16x8 bfr[8];
        #pragma unroll
        for (int k = 0; k < 8; ++k)   // lane reads 16B; 64 lanes pack 64B lines
            bfr[k] = *(const bf16x8*)&Wc[m * 256 + k * 32 + q * 8];
        bf16x8 b8 = (bf16x8)0;        // W1 rows (k'<16) + W0 (k'=16)
        if (q < 2) b8 = *(const bf16x8*)&W1g[c * 256 + m * 16 + q * 8];
        if (q == 2) b8[0] = W0g[c * 16 + m];

        #pragma unroll
        for (int t = 0; t < 2; ++t) {
            const int n_at = nBase + t * 16 + m;    // lane's atom (all q groups)

            float f[16];
            {
                const float4* fp = (const float4*)(nf + ((size_t)n_at * NCHAN + c) * 16);
                #pragma unroll
                for (int j = 0; j < 4; ++j) {
                    float4 v = fp[j];
                    f[4*j] = v.x; f[4*j+1] = v.y; f[4*j+2] = v.z; f[4*j+3] = v.w;
                }
            }
            float fi8[8];                           // f[(q&1)*8 + j]
            #pragma unroll
            for (int j = 0; j < 8; ++j) fi8[j] = (q & 1) ? f[8 + j] : f[j];
            float fq[4];                            // f[q*4 + j] (epilogue dot)
            #pragma unroll
            for (int j = 0; j < 4; ++j) {
                float lo = (q & 1) ? f[4 + j]  : f[j];
                float hi = (q & 1) ? f[12 + j] : f[8 + j];
                fq[j] = (q & 2) ? hi : lo;
            }

            // B-frag for the W1/W0 chunk: q<2 -> f[q*8+j]; q==2,j==0 -> 1.0
            uint4 a8w;
            a8w.x = pk_bf(fi8[0], fi8[1]); a8w.y = pk_bf(fi8[2], fi8[3]);
            a8w.z = pk_bf(fi8[4], fi8[5]); a8w.w = pk_bf(fi8[6], fi8[7]);
            if (q >= 2) { a8w.x = (q == 2) ? 0x3F80u : 0u; a8w.y = 0; a8w.z = 0; a8w.w = 0; }

            f32x4 accA = {0.f,0.f,0.f,0.f}, accB = accA, accC = accA;
            accC = __builtin_amdgcn_mfma_f32_16x16x32_bf16(
                       b8, __builtin_bit_cast(bf16x8, a8w), accC, 0, 0, 0);
            #pragma unroll
            for (int k = 0; k < 8; ++k) {
                // P[k] = f_y*f_i ; y = k*2 + (q>>1), i = (q&1)*8 + j
                float fy = (q & 2) ? f[2*k + 1] : f[2*k];
                uint4 aw;
                aw.x = pk_bf(fy * fi8[0], fy * fi8[1]);
                aw.y = pk_bf(fy * fi8[2], fy * fi8[3]);
                aw.z = pk_bf(fy * fi8[4], fy * fi8[5]);
                aw.w = pk_bf(fy * fi8[6], fy * fi8[7]);
                bf16x8 pf = __builtin_bit_cast(bf16x8, aw);
                if (k % 3 == 0)      accA = __builtin_amdgcn_mfma_f32_16x16x32_bf16(bfr[k], pf, accA, 0, 0, 0);
                else if (k % 3 == 1) accB = __builtin_amdgcn_mfma_f32_16x16x32_bf16(bfr[k], pf, accB, 0, 0, 0);
                else                 accC = __builtin_amdgcn_mfma_f32_16x16x32_bf16(bfr[k], pf, accC, 0, 0, 0);
            }
            f32x4 acc = (accA + accB) + accC;       // D[x=q*4+r][atom=m]

            // out[n] = sum_x f[n,x]*D[x,n]: own-register dot + xor16/32 reduce
            float s = acc[0]*fq[0] + acc[1]*fq[1] + acc[2]*fq[2] + acc[3]*fq[3];
            s += __shfl_xor(s, 16, 64);
            s += __shfl_xor(s, 32, 64);
            if (q == 0) Ot[wave * 8 + ch][t * 16 + m] = s;   // 16 banks, clean
        }
    }
    __syncthreads();

    // --- coalesced writeout: block owns rows nBase..nBase+31, cols c0..c0+31
    const int a = tid >> 3, cg = tid & 7;           // 32 atoms x 8 col-groups
    float4 v = { Ot[cg*4+0][a], Ot[cg*4+1][a], Ot[cg*4+2][a], Ot[cg*4+3][a] };
    *(float4*)&out[(size_t)(nBase + a) * NCHAN + blockIdx.y * 32 + cg * 4] = v;
}

extern "C" void kernel_launch(void* const* d_in, const int* in_sizes, int n_in,
                              void* d_out, int out_size, void* d_ws, size_t ws_size,
                              hipStream_t stream)
{
    const float* nf = (const float*)d_in[0];
    const float* U2 = (const float*)d_in[1];
    const float* U1 = (const float*)d_in[2];
    const float* U0 = (const float*)d_in[3];
    const float* w2 = (const float*)d_in[4];
    const float* w1 = (const float*)d_in[5];
    const float* w0 = (const float*)d_in[6];
    float* out = (float*)d_out;

    precompute_kernel<<<1092, 256, 0, stream>>>(U2, U1, U0, w2, w1, w0, d_ws);

    dim3 grid(NATOMS / 32, 2);                      // (625, 2), exact cover
    contract_kernel<<<grid, 256, 0, stream>>>(nf, d_ws, out);
}